// Round 8
// baseline (112.502 us; speedup 1.0000x reference)
//
#include <hip/hip_runtime.h>
#include <stdint.h>

#define NQ 14
#define STATE 16384
#define BATCH 512
#define THREADS 512
#define PER 32
#define STRIDE 132                 // 128 + 4-word pad: bank-rotates rows, keeps 16B align
#define LDS_WORDS (128 * STRIDE)  // 16896 words = 67584 B (dynamic LDS, 2 blocks/CU)
#define SCALE 6.103515625e-05f    // 2^-14: both FWHT norms folded into the rotation

typedef float v2f __attribute__((ext_vector_type(2)));  // (re, im) -> v_pk_* ops
typedef float f4v __attribute__((ext_vector_type(4)));  // nt-capable 16B vector
typedef unsigned int u4v __attribute__((ext_vector_type(4)));

__device__ __forceinline__ int adr(int row, int col) { return row * STRIDE + col; }

// bf16-pair packing: one b32 word = complex element (re lo16, im hi16), RN-ish.
__device__ __forceinline__ uint32_t pkc(v2f v) {
    uint32_t rb = __float_as_uint(v[0]) + 0x8000u;
    uint32_t ib = __float_as_uint(v[1]) + 0x8000u;
    return (ib & 0xFFFF0000u) | (rb >> 16);
}
__device__ __forceinline__ v2f upkc(uint32_t w) {
    v2f v;
    v[0] = __uint_as_float(w << 16);
    v[1] = __uint_as_float(w & 0xFFFF0000u);
    return v;
}

// Packed complex FWHT over register bits m=1..MAXM.
template <int MAXM>
__device__ __forceinline__ void fwht_pk(v2f (&x)[PER]) {
#pragma unroll
    for (int m = 1; m <= MAXM; m <<= 1) {
#pragma unroll
        for (int r = 0; r < PER; ++r) {
            if (!(r & m)) {
                v2f a = x[r], b = x[r | m];
                x[r] = a + b;
                x[r | m] = a - b;
            }
        }
    }
}
// Scalar FWHT (transform 2 is real-only: harness output = real part).
template <int MAXM>
__device__ __forceinline__ void fwht_s(float (&x)[PER]) {
#pragma unroll
    for (int m = 1; m <= MAXM; m <<= 1) {
#pragma unroll
        for (int r = 0; r < PER; ++r) {
            if (!(r & m)) {
                float a = x[r], b = x[r | m];
                x[r] = a + b;
                x[r | m] = a - b;
            }
        }
    }
}

// Word-address maps (word index = complex elem in t1, real f32 in t2):
// L0: s = (r>>2)*2048 + t*4 + (r&3)   reg bits s{0,1,11,12,13}; rows cross-wave
// L1: s = (t>>2)*128 + r*4 + (t&3)    reg bits s{2..6};  rows [16w,16w+16): wave-local
// L2: s = (t>>6)*2048 + (r&15)*128 + (r>>4)*64 + ((t>>2)&15)*4 + (t&3)
//     reg bits s{7..10} (+s6 redundant); rows [16w,16w+16): wave-local
// LDS address of s: adr(s>>7, s&127).  All patterns <=2 lanes/bank (free).

__global__ void __launch_bounds__(THREADS, 4)
rx_kernel(const float* __restrict__ phr, const float* __restrict__ phim,
          const float* __restrict__ th, float* __restrict__ out,
          long long out_limit) {
    extern __shared__ float lds[];   // 67584 B -> 2 blocks/CU (135 KiB of 160)
    uint32_t* ldsw = (uint32_t*)lds;
    const int b = blockIdx.x;
    const int t = threadIdx.x;

    // ---- thetas first: start the w[] dependency chain earliest ----
    float w[NQ];   // w[k] multiplies bit k (LSB) of s: w[k] = theta[13-k]
#pragma unroll
    for (int k = 0; k < NQ; ++k) w[k] = th[b * NQ + 13 - k];

    v2f x[PER];
    const float* pr = phr + (size_t)b * STATE;
    const float* pi = phim + (size_t)b * STATE;
#pragma unroll
    for (int i = 0; i < 8; ++i) {
        // read-once streams: non-temporal (skip L2 retention)
        f4v a = __builtin_nontemporal_load((const f4v*)(pr + i * 2048 + t * 4));
        f4v c = __builtin_nontemporal_load((const f4v*)(pi + i * 2048 + t * 4));
        x[4 * i]     = v2f{a.x, c.x};
        x[4 * i + 1] = v2f{a.y, c.y};
        x[4 * i + 2] = v2f{a.z, c.z};
        x[4 * i + 3] = v2f{a.w, c.w};
    }

    // ---- transform 1: L0 bits {0,1,11,12,13} (complex fp32, packed math) ----
    fwht_pk<16>(x);

    // XCHG1 (L0 -> L1): ONE pass, complex as bf16-pair words. 1 barrier.
    {
#pragma unroll
        for (int i = 0; i < 8; ++i) {
            u4v v = {pkc(x[4 * i]), pkc(x[4 * i + 1]),
                     pkc(x[4 * i + 2]), pkc(x[4 * i + 3])};
            *(u4v*)&ldsw[adr(i * 16 + (t >> 5), (t & 31) * 4)] = v;    // b128
        }
        __syncthreads();                                               // S1
        const int base = adr(t >> 2, t & 3);
#pragma unroll
        for (int r = 0; r < PER; ++r) x[r] = upkc(ldsw[base + r * 4]); // read2-merged
    }

    // ---- L1 bits {2..6} ----
    fwht_pk<16>(x);

    // XCHG2 (L1 -> L2): wave-local rows both sides -> NO barrier; packed words.
    {
        const int base = adr(t >> 2, t & 3);
#pragma unroll
        for (int r = 0; r < PER; ++r) ldsw[base + r * 4] = pkc(x[r]);  // write2-merged
        const int base2 = adr((t >> 6) * 16, ((t >> 2) & 15) * 4 + (t & 3));
#pragma unroll
        for (int r = 0; r < PER; ++r)
            x[r] = upkc(ldsw[base2 + (r & 15) * STRIDE + (r >> 4) * 64]);
    }

    // ---- L2 bits {7..10} ----
    fwht_pk<8>(x);

    // ---- rotation; output = REAL part only, so im dies here; fold 2^-14 ----
    float tp = 0.f;
    if (t & 1)   tp += w[0];
    if (t & 2)   tp += w[1];
    if (t & 4)   tp += w[2];
    if (t & 8)   tp += w[3];
    if (t & 16)  tp += w[4];
    if (t & 32)  tp += w[5];
    if (t & 64)  tp += w[11];
    if (t & 128) tp += w[12];
    if (t & 256) tp += w[13];
    float p[PER];
#pragma unroll
    for (int r = 0; r < PER; ++r) {
        float ph = tp;
        if (r & 1)  ph += w[7];
        if (r & 2)  ph += w[8];
        if (r & 4)  ph += w[9];
        if (r & 8)  ph += w[10];
        if (r & 16) ph += w[6];
        const float ang = -0.5f * ph;
        const float sn = __sinf(ang);
        const float cs = __cosf(ang);
        p[r] = (x[r][0] * cs - x[r][1] * sn) * SCALE;
    }

    // ---- transform 2 (reverse order, real fp32): L2 bits {7..10} ----
    fwht_s<8>(p);

    // XCHG3 (L2 -> L1): wave-local -> NO barrier; f32 words.
    {
        const int base2 = adr((t >> 6) * 16, ((t >> 2) & 15) * 4 + (t & 3));
#pragma unroll
        for (int r = 0; r < PER; ++r)
            lds[base2 + (r & 15) * STRIDE + (r >> 4) * 64] = p[r];
        const int base = adr(t >> 2, t & 3);
#pragma unroll
        for (int r = 0; r < PER; ++r) p[r] = lds[base + r * 4];
    }

    // ---- L1 bits {2..6} ----
    fwht_s<16>(p);

    // XCHG4 (L1 -> L0): wave-local write, 1 barrier, cross-wave b128 reads.
    {
        const int base = adr(t >> 2, t & 3);
#pragma unroll
        for (int r = 0; r < PER; ++r) lds[base + r * 4] = p[r];
        __syncthreads();                                               // S2
#pragma unroll
        for (int i = 0; i < 8; ++i) {
            float4 v = *(const float4*)&lds[adr(i * 16 + (t >> 5), (t & 31) * 4)];
            p[4 * i] = v.x; p[4 * i + 1] = v.y; p[4 * i + 2] = v.z; p[4 * i + 3] = v.w;
        }
    }

    // ---- L0 bits {0,1,11,12,13} ----
    fwht_s<16>(p);

    // ---- store real part, (512,16384) row-major, guarded, NON-TEMPORAL ----
    // nt store: no read-for-ownership fetch of output lines, no L2 retention.
    float* o = out + (size_t)b * STATE;
    const long long base = (long long)b * STATE;
#pragma unroll
    for (int i = 0; i < 8; ++i) {
        const int s0 = i * 2048 + t * 4;
        if (base + s0 + 3 < out_limit) {
            f4v v = {p[4 * i], p[4 * i + 1], p[4 * i + 2], p[4 * i + 3]};
            __builtin_nontemporal_store(v, (f4v*)(o + s0));
        }
    }
}

extern "C" void kernel_launch(void* const* d_in, const int* in_sizes, int n_in,
                              void* d_out, int out_size, void* d_ws, size_t ws_size,
                              hipStream_t stream) {
    const float* phr  = (const float*)d_in[0];
    const float* phim = (const float*)d_in[1];
    const float* th   = (const float*)d_in[2];
    float* out = (float*)d_out;
    // Dynamic LDS 67584 B > 64 KiB: raise the per-kernel dynamic-LDS cap.
    (void)hipFuncSetAttribute((const void*)rx_kernel,
                              hipFuncAttributeMaxDynamicSharedMemorySize,
                              LDS_WORDS * (int)sizeof(float));
    rx_kernel<<<BATCH, THREADS, LDS_WORDS * sizeof(float), stream>>>(
        phr, phim, th, out, (long long)out_size);
}